// Round 13
// baseline (870.850 us; speedup 1.0000x reference)
//
#include <hip/hip_runtime.h>

#define BATCH 256
#define TLEN  512
#define DIN   64
#define HID   128
#define HIDP  (HID + 8)      // padded y0buf row (bank-spread)
#define NOUT  40
#define SC    16
#define NCH   (TLEN / SC)    // 32 chunks per layer

typedef _Float16 f16x8 __attribute__((ext_vector_type(8)));
typedef float    f32x4 __attribute__((ext_vector_type(4)));

#define MFMA16(a, b, c) __builtin_amdgcn_mfma_f32_16x16x32_f16((a), (b), (c), 0, 0, 0)
#define SCHED_FENCE() __builtin_amdgcn_sched_barrier(0)

// LDS-visibility barrier only: no vmcnt drain.
#define BARRIER() do {                                      \
    asm volatile("s_waitcnt lgkmcnt(0)" ::: "memory");      \
    __builtin_amdgcn_s_barrier();                           \
} while (0)

static __device__ __forceinline__ f16x8 pack8(float4 a, float4 b) {
    f16x8 v;
    v[0] = (_Float16)a.x; v[1] = (_Float16)a.y; v[2] = (_Float16)a.z; v[3] = (_Float16)a.w;
    v[4] = (_Float16)b.x; v[5] = (_Float16)b.y; v[6] = (_Float16)b.z; v[7] = (_Float16)b.w;
    return v;
}
static __device__ __forceinline__ float sig_(float x) {
    return __builtin_amdgcn_rcpf(1.0f + __expf(-x));
}
static __device__ __forceinline__ float tanh_(float x) {
    return fmaf(-2.0f, __builtin_amdgcn_rcpf(__expf(2.0f * x) + 1.0f), 1.0f);
}
static __device__ __forceinline__ f32x4 splat4(float v) { return (f32x4){v, v, v, v}; }

// Weight fragment loader; uses kernel-local `kg`. k = kt*32 + kg*8 + j.
#define LD8(base, g, K, kt) pack8(*(const float4*)((base) + (size_t)(g) * (K) + (kt) * 32 + kg * 8), \
                                  *(const float4*)((base) + (size_t)(g) * (K) + (kt) * 32 + kg * 8 + 4))

// ====== Fused 2-layer LSTM, LAYER-SPECIALIZED WAVES, l1 one chunk behind ======
// 256 blocks (one batch) x 512 thr. Waves 0-3: layer 0, hid slice [w*32,w*32+32).
// Waves 4-7: layer 1, same hid slicing. Per wave: 32 Wh frags = 128 AGPR (one
// layer only) + ~95 arch regs -> fits 256 budget at 2 waves/SIMD (no spill).
// Steady step: each wave 32 MFMA (8 chains) + 2-cell ACT; one barrier; both
// layers advance per step. y0 passes l0->l1 via LDS ring at chunk granularity.
__global__ void __attribute__((amdgpu_flat_work_group_size(512, 512), amdgpu_waves_per_eu(2, 2)))
lstm_fused(const float* __restrict__ x,
           const float* __restrict__ Wih0, const float* __restrict__ Whh0,
           const float* __restrict__ bih0, const float* __restrict__ bhh0,
           const float* __restrict__ Wih1, const float* __restrict__ Whh1,
           const float* __restrict__ bih1, const float* __restrict__ bhh1,
           const float* __restrict__ Wfc,  const float* __restrict__ bfc,
           float* __restrict__ out)
{
    const int b    = blockIdx.x;
    const int tid  = threadIdx.x;
    const int lane = tid & 63, wave = tid >> 6;
    const int col  = lane & 15, kg = lane >> 4;
    const bool isL0 = (wave < 4);
    const int  w4   = wave & 3;
    const int  hidA = w4 * 32 + col;
    const int  hidB = hidA + 16;

    __shared__ __align__(16) float    xacc[SC * HID * 4];   // 32 KB (l0 input proj)
    __shared__ __align__(16) float    yacc[SC * HID * 4];   // 32 KB (l1 input proj)
    __shared__ __align__(16) _Float16 h0_lds[2][HID];
    __shared__ __align__(16) _Float16 h1_lds[2][HID];
    __shared__ __align__(16) _Float16 y0buf[2][SC][HIDP];   // ~8.7 KB ring

    // role-uniform pointers
    const float* Whh = isL0 ? Whh0 : Whh1;
    const float* Wih = isL0 ? Wih0 : Wih1;
    const float* bi  = isL0 ? bih0 : bih1;
    const float* bh  = isL0 ? bhh0 : bhh1;
    float* myacc = isL0 ? xacc : yacc;
    _Float16 (*myh)[HID] = isL0 ? h0_lds : h1_lds;

    // ---- recurrent weights for THIS wave's layer: 32 frags -> 128 AGPR ----
    f16x8 WA00 = LD8(Whh, 0 * HID + hidA, HID, 0), WA01 = LD8(Whh, 0 * HID + hidA, HID, 1);
    f16x8 WA02 = LD8(Whh, 0 * HID + hidA, HID, 2), WA03 = LD8(Whh, 0 * HID + hidA, HID, 3);
    f16x8 WA10 = LD8(Whh, 1 * HID + hidA, HID, 0), WA11 = LD8(Whh, 1 * HID + hidA, HID, 1);
    f16x8 WA12 = LD8(Whh, 1 * HID + hidA, HID, 2), WA13 = LD8(Whh, 1 * HID + hidA, HID, 3);
    f16x8 WA20 = LD8(Whh, 2 * HID + hidA, HID, 0), WA21 = LD8(Whh, 2 * HID + hidA, HID, 1);
    f16x8 WA22 = LD8(Whh, 2 * HID + hidA, HID, 2), WA23 = LD8(Whh, 2 * HID + hidA, HID, 3);
    f16x8 WA30 = LD8(Whh, 3 * HID + hidA, HID, 0), WA31 = LD8(Whh, 3 * HID + hidA, HID, 1);
    f16x8 WA32 = LD8(Whh, 3 * HID + hidA, HID, 2), WA33 = LD8(Whh, 3 * HID + hidA, HID, 3);
    f16x8 WB00 = LD8(Whh, 0 * HID + hidB, HID, 0), WB01 = LD8(Whh, 0 * HID + hidB, HID, 1);
    f16x8 WB02 = LD8(Whh, 0 * HID + hidB, HID, 2), WB03 = LD8(Whh, 0 * HID + hidB, HID, 3);
    f16x8 WB10 = LD8(Whh, 1 * HID + hidB, HID, 0), WB11 = LD8(Whh, 1 * HID + hidB, HID, 1);
    f16x8 WB12 = LD8(Whh, 1 * HID + hidB, HID, 2), WB13 = LD8(Whh, 1 * HID + hidB, HID, 3);
    f16x8 WB20 = LD8(Whh, 2 * HID + hidB, HID, 0), WB21 = LD8(Whh, 2 * HID + hidB, HID, 1);
    f16x8 WB22 = LD8(Whh, 2 * HID + hidB, HID, 2), WB23 = LD8(Whh, 2 * HID + hidB, HID, 3);
    f16x8 WB30 = LD8(Whh, 3 * HID + hidB, HID, 0), WB31 = LD8(Whh, 3 * HID + hidB, HID, 1);
    f16x8 WB32 = LD8(Whh, 3 * HID + hidB, HID, 2), WB33 = LD8(Whh, 3 * HID + hidB, HID, 3);
    asm("" : "+a"(WA00), "+a"(WA01), "+a"(WA02), "+a"(WA03),
             "+a"(WA10), "+a"(WA11), "+a"(WA12), "+a"(WA13));
    asm("" : "+a"(WA20), "+a"(WA21), "+a"(WA22), "+a"(WA23),
             "+a"(WA30), "+a"(WA31), "+a"(WA32), "+a"(WA33));
    asm("" : "+a"(WB00), "+a"(WB01), "+a"(WB02), "+a"(WB03),
             "+a"(WB10), "+a"(WB11), "+a"(WB12), "+a"(WB13));
    asm("" : "+a"(WB20), "+a"(WB21), "+a"(WB22), "+a"(WB23),
             "+a"(WB30), "+a"(WB31), "+a"(WB32), "+a"(WB33));

    float ccA = 0.f, ccB = 0.f, hvA = 0.f, hvB = 0.f;
    if (tid < HID) { h0_lds[0][tid] = (_Float16)0.f; h1_lds[0][tid] = (_Float16)0.f; }

// ---- XPROJ (l0 waves): 4 single-gate passes; A held (16 regs), W transient ----
#define XP_PASS(N, A0, A1) do {                                                  \
    f16x8 Wt0 = LD8(Wih, (N) * HID + hidA, DIN, 0);                              \
    f16x8 Wt1 = LD8(Wih, (N) * HID + hidA, DIN, 1);                              \
    f16x8 Wu0 = LD8(Wih, (N) * HID + hidB, DIN, 0);                              \
    f16x8 Wu1 = LD8(Wih, (N) * HID + hidB, DIN, 1);                              \
    f32x4 gA = splat4(bi[(N) * HID + hidA] + bh[(N) * HID + hidA]);              \
    f32x4 gB = splat4(bi[(N) * HID + hidB] + bh[(N) * HID + hidB]);              \
    gA = MFMA16(A0, Wt0, gA); gA = MFMA16(A1, Wt1, gA);                          \
    gB = MFMA16(A0, Wu0, gB); gB = MFMA16(A1, Wu1, gB);                          \
    _Pragma("unroll") for (int r = 0; r < 4; ++r) {                              \
        myacc[((kg * 4 + r) * HID + hidA) * 4 + (N)] = gA[r];                    \
        myacc[((kg * 4 + r) * HID + hidB) * 4 + (N)] = gB[r];                    \
    }                                                                            \
} while (0)

#define XPROJ(C) do {                                                            \
    const float* pa = x + (size_t)b * TLEN * DIN                                 \
                        + (size_t)((C) * SC + col) * DIN + kg * 8;               \
    f16x8 A0 = pack8(*(const float4*)pa,        *(const float4*)(pa + 4));       \
    f16x8 A1 = pack8(*(const float4*)(pa + 32), *(const float4*)(pa + 36));      \
    XP_PASS(0, A0, A1); SCHED_FENCE();                                           \
    XP_PASS(1, A0, A1); SCHED_FENCE();                                           \
    XP_PASS(2, A0, A1); SCHED_FENCE();                                           \
    XP_PASS(3, A0, A1);                                                          \
} while (0)

// ---- YPROJ (l1 waves): 4 single-gate passes; A re-read from padded y0buf ----
#define YP_PASS(C, N) do {                                                       \
    const _Float16* pa = &y0buf[((C) - 1) & 1][col][kg * 8];                     \
    f16x8 A0 = *(const f16x8*)pa;                                                \
    f16x8 A1 = *(const f16x8*)(pa + 32);                                         \
    f16x8 A2 = *(const f16x8*)(pa + 64);                                         \
    f16x8 A3 = *(const f16x8*)(pa + 96);                                         \
    f16x8 Wt0 = LD8(Wih, (N) * HID + hidA, HID, 0);                              \
    f16x8 Wt1 = LD8(Wih, (N) * HID + hidA, HID, 1);                              \
    f16x8 Wt2 = LD8(Wih, (N) * HID + hidA, HID, 2);                              \
    f16x8 Wt3 = LD8(Wih, (N) * HID + hidA, HID, 3);                              \
    f16x8 Wu0 = LD8(Wih, (N) * HID + hidB, HID, 0);                              \
    f16x8 Wu1 = LD8(Wih, (N) * HID + hidB, HID, 1);                              \
    f16x8 Wu2 = LD8(Wih, (N) * HID + hidB, HID, 2);                              \
    f16x8 Wu3 = LD8(Wih, (N) * HID + hidB, HID, 3);                              \
    f32x4 gA = splat4(bi[(N) * HID + hidA] + bh[(N) * HID + hidA]);              \
    f32x4 gB = splat4(bi[(N) * HID + hidB] + bh[(N) * HID + hidB]);              \
    gA = MFMA16(A0, Wt0, gA); gA = MFMA16(A1, Wt1, gA);                          \
    gA = MFMA16(A2, Wt2, gA); gA = MFMA16(A3, Wt3, gA);                          \
    gB = MFMA16(A0, Wu0, gB); gB = MFMA16(A1, Wu1, gB);                          \
    gB = MFMA16(A2, Wu2, gB); gB = MFMA16(A3, Wu3, gB);                          \
    _Pragma("unroll") for (int r = 0; r < 4; ++r) {                              \
        myacc[((kg * 4 + r) * HID + hidA) * 4 + (N)] = gA[r];                    \
        myacc[((kg * 4 + r) * HID + hidB) * 4 + (N)] = gB[r];                    \
    }                                                                            \
} while (0)

#define YPROJ(C) do {                                                            \
    YP_PASS(C, 0); SCHED_FENCE();                                                \
    YP_PASS(C, 1); SCHED_FENCE();                                                \
    YP_PASS(C, 2); SCHED_FENCE();                                                \
    YP_PASS(C, 3);                                                               \
} while (0)

// ---- unified steady step: 32 MFMA (8 chains of 4) + 2-cell ACT ----
#define STEP_CORE(S, P, YB) do {                                                 \
    f32x4 xiA = *(const f32x4*)&myacc[((S) * HID + hidA) * 4];                   \
    f32x4 xiB = *(const f32x4*)&myacc[((S) * HID + hidB) * 4];                   \
    const _Float16* hb = &myh[P][0];                                             \
    f16x8 h0 = *(const f16x8*)(hb + kg * 8);                                     \
    f16x8 h1 = *(const f16x8*)(hb + 32 + kg * 8);                                \
    f16x8 h2 = *(const f16x8*)(hb + 64 + kg * 8);                                \
    f16x8 h3 = *(const f16x8*)(hb + 96 + kg * 8);                                \
    f32x4 aA0 = MFMA16(h0, WA00, xiA);                                           \
    f32x4 aA1 = MFMA16(h0, WA10, splat4(xiA[1]));                                \
    f32x4 aA2 = MFMA16(h0, WA20, splat4(xiA[2]));                                \
    f32x4 aA3 = MFMA16(h0, WA30, splat4(xiA[3]));                                \
    f32x4 aB0 = MFMA16(h0, WB00, xiB);                                           \
    f32x4 aB1 = MFMA16(h0, WB10, splat4(xiB[1]));                                \
    f32x4 aB2 = MFMA16(h0, WB20, splat4(xiB[2]));                                \
    f32x4 aB3 = MFMA16(h0, WB30, splat4(xiB[3]));                                \
    aA0 = MFMA16(h1, WA01, aA0); aA1 = MFMA16(h1, WA11, aA1);                    \
    aA2 = MFMA16(h1, WA21, aA2); aA3 = MFMA16(h1, WA31, aA3);                    \
    aB0 = MFMA16(h1, WB01, aB0); aB1 = MFMA16(h1, WB11, aB1);                    \
    aB2 = MFMA16(h1, WB21, aB2); aB3 = MFMA16(h1, WB31, aB3);                    \
    aA0 = MFMA16(h2, WA02, aA0); aA1 = MFMA16(h2, WA12, aA1);                    \
    aA2 = MFMA16(h2, WA22, aA2); aA3 = MFMA16(h2, WA32, aA3);                    \
    aB0 = MFMA16(h2, WB02, aB0); aB1 = MFMA16(h2, WB12, aB1);                    \
    aB2 = MFMA16(h2, WB22, aB2); aB3 = MFMA16(h2, WB32, aB3);                    \
    aA0 = MFMA16(h3, WA03, aA0); aA1 = MFMA16(h3, WA13, aA1);                    \
    aA2 = MFMA16(h3, WA23, aA2); aA3 = MFMA16(h3, WA33, aA3);                    \
    aB0 = MFMA16(h3, WB03, aB0); aB1 = MFMA16(h3, WB13, aB1);                    \
    aB2 = MFMA16(h3, WB23, aB2); aB3 = MFMA16(h3, WB33, aB3);                    \
    float ivA = sig_(aA0[0]), fvA = sig_(aA1[0]);                                \
    float gvA = tanh_(aA2[0]), ovA = sig_(aA3[0]);                               \
    ccA = fmaf(fvA, ccA, ivA * gvA);                                             \
    hvA = ovA * tanh_(ccA);                                                      \
    float ivB = sig_(aB0[0]), fvB = sig_(aB1[0]);                                \
    float gvB = tanh_(aB2[0]), ovB = sig_(aB3[0]);                               \
    ccB = fmaf(fvB, ccB, ivB * gvB);                                             \
    hvB = ovB * tanh_(ccB);                                                      \
    if (kg == 0) {                                                               \
        _Float16 hA = (_Float16)hvA, hB = (_Float16)hvB;                         \
        myh[(P) ^ 1][hidA] = hA;                                                 \
        myh[(P) ^ 1][hidB] = hB;                                                 \
        if (isL0) { y0buf[YB][S][hidA] = hA; y0buf[YB][S][hidB] = hB; }          \
    }                                                                            \
} while (0)

    BARRIER();   // h init visible

    for (int c = 0; c <= NCH; ++c) {
        const bool act = isL0 ? (c < NCH) : (c >= 1);
        if (act) {
            if (isL0) XPROJ(c);
            else      YPROJ(c);
        }
        BARRIER();
        const int yb = c & 1;
        for (int s = 0; s < SC; s += 2) {
            if (act) { STEP_CORE(s, 0, yb); }
            BARRIER();
            if (act) { STEP_CORE(s + 1, 1, yb); }
            BARRIER();
        }
    }

    // ---- fused FC: h1 final lives in l1-waves' hvA/hvB ----
    if (!isL0 && kg == 0) { xacc[hidA] = hvA; xacc[hidB] = hvB; }
    BARRIER();
    if (tid < NOUT) {
        const float4* w   = (const float4*)(Wfc + (size_t)tid * HID);
        const float4* hvv = (const float4*)xacc;
        float acc = bfc[tid];
        #pragma unroll
        for (int q = 0; q < HID / 4; ++q) {
            float4 wv = w[q]; float4 h4 = hvv[q];
            acc = fmaf(wv.x, h4.x, fmaf(wv.y, h4.y, fmaf(wv.z, h4.z, fmaf(wv.w, h4.w, acc))));
        }
        out[(size_t)b * NOUT + tid] = acc;
    }
}

extern "C" void kernel_launch(void* const* d_in, const int* in_sizes, int n_in,
                              void* d_out, int out_size, void* d_ws, size_t ws_size,
                              hipStream_t stream) {
    const float* x    = (const float*)d_in[0];
    const float* Wih0 = (const float*)d_in[1];
    const float* Whh0 = (const float*)d_in[2];
    const float* bih0 = (const float*)d_in[3];
    const float* bhh0 = (const float*)d_in[4];
    const float* Wih1 = (const float*)d_in[5];
    const float* Whh1 = (const float*)d_in[6];
    const float* bih1 = (const float*)d_in[7];
    const float* bhh1 = (const float*)d_in[8];
    const float* Wfc  = (const float*)d_in[9];
    const float* bfc  = (const float*)d_in[10];
    float* out = (float*)d_out;

    lstm_fused<<<BATCH, 512, 0, stream>>>(x, Wih0, Whh0, bih0, bhh0,
                                          Wih1, Whh1, bih1, bhh1, Wfc, bfc, out);
}